// Round 9
// baseline (299.657 us; speedup 1.0000x reference)
//
#include <hip/hip_runtime.h>
#include <math.h>

#define NB 32
#define NC 256
#define NH 64
#define NW 64
#define NHW (NH * NW)          // 4096
#define EPS_ 1e-5f

typedef float f32x4 __attribute__((ext_vector_type(4)));

// ---------------------------------------------------------------------------
// K1: channel pooling. pooled[b][0][h][w] = max_c x, pooled[b][1][h][w] = mean_c x
// Block = 512 threads = 8 waves; wave w owns 32 channels, lane = hw-quad.
// ---------------------------------------------------------------------------
__global__ __launch_bounds__(512) void pool_k(const float* __restrict__ x,
                                              float* __restrict__ pooled) {
    const int tid = threadIdx.x;
    const int chunk = tid >> 6;           // 0..7 (32 channels each)
    const int lane = tid & 63;            // hw-quad within block's 64-quad group
    const int q = blockIdx.x * 64 + lane; // global hw-quad in [0, NB*NHW/4)
    const int b = q >> 10;                // NHW/4 = 1024
    const int hwq = q & 1023;

    const float4* __restrict__ xq = (const float4*)x;
    const int base = b * NC * (NHW / 4) + hwq;

    float4 mx = make_float4(-INFINITY, -INFINITY, -INFINITY, -INFINITY);
    float4 sm = make_float4(0.f, 0.f, 0.f, 0.f);
    const int c0 = chunk * 32;
    #pragma unroll 8
    for (int c = c0; c < c0 + 32; ++c) {
        float4 v = xq[base + c * (NHW / 4)];
        mx.x = fmaxf(mx.x, v.x); mx.y = fmaxf(mx.y, v.y);
        mx.z = fmaxf(mx.z, v.z); mx.w = fmaxf(mx.w, v.w);
        sm.x += v.x; sm.y += v.y; sm.z += v.z; sm.w += v.w;
    }

    __shared__ float4 smax[8][64];   // 8 KiB
    __shared__ float4 ssum[8][64];   // 8 KiB
    smax[chunk][lane] = mx;
    ssum[chunk][lane] = sm;
    __syncthreads();

    if (tid < 64) {
        float4 m = smax[0][tid];
        float4 s = ssum[0][tid];
        #pragma unroll
        for (int k = 1; k < 8; ++k) {
            float4 m2 = smax[k][tid];
            float4 s2 = ssum[k][tid];
            m.x = fmaxf(m.x, m2.x); m.y = fmaxf(m.y, m2.y);
            m.z = fmaxf(m.z, m2.z); m.w = fmaxf(m.w, m2.w);
            s.x += s2.x; s.y += s2.y; s.z += s2.z; s.w += s2.w;
        }
        const float inv = 1.f / (float)NC;
        float4 mean = make_float4(s.x * inv, s.y * inv, s.z * inv, s.w * inv);
        float4* __restrict__ pq = (float4*)pooled;
        pq[(b * 2 + 0) * (NHW / 4) + hwq] = m;
        pq[(b * 2 + 1) * (NHW / 4) + hwq] = mean;
    }
}

// ---------------------------------------------------------------------------
// K2 (fused att+mul, v2): block = (b, 4 consecutive h rows). Phase A: load
// zero-padded pooled halo [10 rows][2 ch][72 cols]; each of the 256 threads
// computes ONE att value (294 FMAs). Phase B: each wave owns channels
// wv, wv+4, ... (64 channels); a channel's 4-row slice = 64 quads = one
// wave-wide 1 KiB contiguous transaction; per-lane att quad is hoisted out
// of the inner loop -> pure load/mul/NT-store at 16 KiB stride.
// Grid 512 blocks x 256 thr; LDS ~6.8 KiB.
// ---------------------------------------------------------------------------
__global__ __launch_bounds__(256) void attmul_k(
    const float* __restrict__ x,
    const float* __restrict__ pooled,
    const float* __restrict__ w1, const float* __restrict__ g1,
    const float* __restrict__ be1, const float* __restrict__ m1,
    const float* __restrict__ v1,
    const float* __restrict__ w2, const float* __restrict__ g2,
    const float* __restrict__ be2, const float* __restrict__ m2,
    const float* __restrict__ v2,
    const float* __restrict__ w3, const float* __restrict__ g3,
    const float* __restrict__ be3, const float* __restrict__ m3,
    const float* __restrict__ v3,
    float* __restrict__ out) {
    const int b = blockIdx.x >> 4;       // 32 batches
    const int h4 = blockIdx.x & 15;      // 16 groups of 4 rows
    const int h0 = h4 * 4;
    const int t = threadIdx.x;

    __shared__ float plds[10][2][72];    // zero-padded halo, 5760 B
    __shared__ float att_s[256];

    // Phase A1: fill halo. 1440 entries, up to 6 per thread.
    #pragma unroll
    for (int k = 0; k < 6; ++k) {
        const int idx = t + k * 256;
        if (idx < 1440) {
            const int r = idx / 144;            // 0..9 (halo row)
            const int rem = idx - r * 144;
            const int ci = rem / 72;            // 0..1
            const int col = rem - ci * 72;      // 0..71
            const int y = h0 - 3 + r;
            const int xc = col - 3;
            float v = 0.f;
            if ((unsigned)y < (unsigned)NH && (unsigned)xc < (unsigned)NW)
                v = pooled[((b * 2 + ci) * NH + y) * NW + xc];
            plds[r][ci][col] = v;
        }
    }
    __syncthreads();

    // Phase A2: each thread computes att for (row r = t>>6, col w = t&63).
    {
        const int r = t >> 6;               // 0..3 within the row group
        const int w = t & 63;
        float s1 = 0.f, s2 = 0.f, s3 = 0.f;
        #pragma unroll
        for (int dh = 0; dh < 7; ++dh) {
            #pragma unroll
            for (int ci = 0; ci < 2; ++ci) {
                #pragma unroll
                for (int dw = 0; dw < 7; ++dw) {
                    const float p = plds[r + dh][ci][w + dw];
                    s1 = fmaf(p, w1[ci * 49 + dh * 7 + dw], s1);
                    s2 = fmaf(p, w2[ci * 49 + dw * 7 + dh], s2); // transposed
                    s3 = fmaf(p, w3[ci * 49 + dh * 7 + dw], s3);
                }
            }
        }
        const float sc1 = g1[0] * rsqrtf(v1[0] + EPS_);
        const float sc2 = g2[0] * rsqrtf(v2[0] + EPS_);
        const float sc3 = g3[0] * rsqrtf(v3[0] + EPS_);
        const float y1 = (s1 - m1[0]) * sc1 + be1[0];
        const float y2 = (s2 - m2[0]) * sc2 + be2[0];
        const float y3 = (s3 - m3[0]) * sc3 + be3[0];
        const float a1 = 1.f / (1.f + expf(-y1));
        const float a2 = 1.f / (1.f + expf(-y2));
        const float a3 = 1.f / (1.f + expf(-y3));
        att_s[t] = (a1 + a2 + a3) * (1.f / 3.f);
    }
    __syncthreads();

    // Phase B: wave wv handles channels wv, wv+4, ..., wv+252.
    // Lane l covers quad l of the 4-row slice (row = l>>4, colquad = l&15),
    // so its att quad a4[l] is invariant across channels.
    const f32x4* __restrict__ xq = (const f32x4*)x;
    f32x4* __restrict__ oq = (f32x4*)out;
    const f32x4* __restrict__ a4 = (const f32x4*)att_s;
    const int wv = t >> 6;
    const int l = t & 63;
    const f32x4 a = a4[l];
    int addr = (b * NC + wv) * (NHW / 4) + h4 * 64 + l;
    #pragma unroll 8
    for (int i = 0; i < 64; ++i) {
        const f32x4 v = xq[addr];
        __builtin_nontemporal_store(v * a, &oq[addr]);
        addr += 4 * (NHW / 4);   // skip 4 channels
    }
}

extern "C" void kernel_launch(void* const* d_in, const int* in_sizes, int n_in,
                              void* d_out, int out_size, void* d_ws, size_t ws_size,
                              hipStream_t stream) {
    const float* x  = (const float*)d_in[0];
    const float* w1 = (const float*)d_in[1];
    const float* g1 = (const float*)d_in[2];
    const float* b1 = (const float*)d_in[3];
    const float* m1 = (const float*)d_in[4];
    const float* v1 = (const float*)d_in[5];
    const float* w2 = (const float*)d_in[6];
    const float* g2 = (const float*)d_in[7];
    const float* b2 = (const float*)d_in[8];
    const float* m2 = (const float*)d_in[9];
    const float* v2 = (const float*)d_in[10];
    const float* w3 = (const float*)d_in[11];
    const float* g3 = (const float*)d_in[12];
    const float* b3 = (const float*)d_in[13];
    const float* m3 = (const float*)d_in[14];
    const float* v3 = (const float*)d_in[15];
    float* out = (float*)d_out;

    float* pooled = (float*)d_ws;   // NB*2*NHW floats = 1 MiB

    // K1: 512 blocks x 512 thr (each block: 64 hw-quads x 8 C-chunks of 32)
    pool_k<<<NB * NHW / 4 / 64, 512, 0, stream>>>(x, pooled);
    // K2: one block per (b, 4-row group): 512 blocks x 256 thr
    attmul_k<<<NB * (NH / 4), 256, 0, stream>>>(x, pooled,
        w1, g1, b1, m1, v1, w2, g2, b2, m2, v2, w3, g3, b3, m3, v3, out);
}